// Round 1
// baseline (791.921 us; speedup 1.0000x reference)
//
#include <hip/hip_runtime.h>
#include <math.h>

// ---------------------------------------------------------------------------
// GATRec: 2-layer GAT on 110k nodes, 1M edges (+N self loops).
// Pipeline: build CSR (hist/scan/scatter) -> gemm1+att -> agg1(softmax+ELU)
//           -> gemm2+att -> agg2 -> d_out
// ---------------------------------------------------------------------------

__global__ void hist_kernel(const int* __restrict__ ei, int E, int ET,
                            int* __restrict__ cnt) {
    int e = blockIdx.x * blockDim.x + threadIdx.x;
    if (e >= ET) return;
    int d = (e < E) ? ei[E + e] : (e - E);
    atomicAdd(&cnt[d], 1);
}

__global__ __launch_bounds__(256) void scan_blocks_kernel(
    const int* __restrict__ cnt, int* __restrict__ offs,
    int* __restrict__ bsums, int n) {
    __shared__ int sdata[256];
    int base = blockIdx.x * 4096 + threadIdx.x * 16;
    int vals[16];
    int tsum = 0;
#pragma unroll
    for (int i = 0; i < 16; ++i) {
        int idx = base + i;
        int v = (idx < n) ? cnt[idx] : 0;
        vals[i] = v;
        tsum += v;
    }
    sdata[threadIdx.x] = tsum;
    __syncthreads();
    for (int off = 1; off < 256; off <<= 1) {
        int v = (threadIdx.x >= off) ? sdata[threadIdx.x - off] : 0;
        __syncthreads();
        sdata[threadIdx.x] += v;
        __syncthreads();
    }
    int run = sdata[threadIdx.x] - tsum;  // exclusive prefix of this thread
    if (threadIdx.x == 255) bsums[blockIdx.x] = sdata[255];
#pragma unroll
    for (int i = 0; i < 16; ++i) {
        int idx = base + i;
        if (idx < n) offs[idx] = run;
        run += vals[i];
    }
}

__global__ void scan_small_kernel(int* bsums, int nb) {
    if (blockIdx.x == 0 && threadIdx.x == 0) {
        int run = 0;
        for (int i = 0; i < nb; ++i) {
            int v = bsums[i];
            bsums[i] = run;
            run += v;
        }
    }
}

__global__ void scan_add_kernel(int* __restrict__ offs,
                                const int* __restrict__ bsums, int n, int total) {
    int idx = blockIdx.x * blockDim.x + threadIdx.x;
    if (idx < n) offs[idx] += bsums[idx >> 12];
    if (idx == 0) offs[n] = total;
}

__global__ void scatter_kernel(const int* __restrict__ ei, int E, int ET,
                               int* __restrict__ cursor, int* __restrict__ csr) {
    int e = blockIdx.x * blockDim.x + threadIdx.x;
    if (e >= ET) return;
    int s, d;
    if (e < E) { s = ei[e]; d = ei[E + e]; } else { s = e - E; d = e - E; }
    int pos = atomicAdd(&cursor[d], 1);
    csr[pos] = s;
}

// ---------------------------------------------------------------------------
// GEMM1: h1[r][t] = sum_k x[r][k] * W1[k][t],  t in [0,256), k in [0,64)
// x row r: r < NU ? emb_user[r] : emb_item[r-NU]
// Fused: a_src1[r][h] = sum_c h1[r][h*64+c]*attS[h][c] (wave h reduces), same dst.
// ---------------------------------------------------------------------------
#define G1_ROWS 8
__global__ __launch_bounds__(256) void gemm1_kernel(
    const float* __restrict__ xu, const float* __restrict__ xi, int NU, int Ntot,
    const float* __restrict__ W1, const float* __restrict__ attS,
    const float* __restrict__ attD, float* __restrict__ h1,
    float* __restrict__ as1, float* __restrict__ ad1) {
    __shared__ float xrow[G1_ROWS][64];
    int t = threadIdx.x;
    float w[64];
#pragma unroll
    for (int k = 0; k < 64; ++k) w[k] = W1[k * 256 + t];
    float aS = attS[t];
    float aD = attD[t];
    int lane = t & 63;
    int head = t >> 6;
    int ntiles = (Ntot + G1_ROWS - 1) / G1_ROWS;
    for (int tile = blockIdx.x; tile < ntiles; tile += gridDim.x) {
        int rbase = tile * G1_ROWS;
        __syncthreads();
        for (int i = t; i < G1_ROWS * 64; i += 256) {
            int r = rbase + (i >> 6);
            int k = i & 63;
            float v = 0.f;
            if (r < Ntot) v = (r < NU) ? xu[(size_t)r * 64 + k] : xi[(size_t)(r - NU) * 64 + k];
            xrow[i >> 6][k] = v;
        }
        __syncthreads();
#pragma unroll
        for (int i = 0; i < G1_ROWS; ++i) {
            int r = rbase + i;
            if (r >= Ntot) break;
            float acc = 0.f;
#pragma unroll
            for (int k = 0; k < 64; ++k) acc += xrow[i][k] * w[k];
            h1[(size_t)r * 256 + t] = acc;
            float rs = acc * aS, rd = acc * aD;
#pragma unroll
            for (int msk = 32; msk; msk >>= 1) {
                rs += __shfl_xor(rs, msk);
                rd += __shfl_xor(rd, msk);
            }
            if (lane == 0) {
                as1[(size_t)r * 4 + head] = rs;
                ad1[(size_t)r * 4 + head] = rd;
            }
        }
    }
}

// ---------------------------------------------------------------------------
// AGG1: per node n, online softmax over incoming edges (4 heads),
// out = sum alpha*h1[src], + bias, ELU. One wave per node; lane owns 4 channels.
// ---------------------------------------------------------------------------
__global__ __launch_bounds__(256) void agg1_kernel(
    const float* __restrict__ h1, const float* __restrict__ as1,
    const float* __restrict__ ad1, const int* __restrict__ offs,
    const int* __restrict__ csr, const float* __restrict__ b1,
    float* __restrict__ x2, int N) {
    int wv = threadIdx.x >> 6, lane = threadIdx.x & 63;
    int n = blockIdx.x * 4 + wv;
    if (n >= N) return;
    int head = lane >> 4;  // channels 4*lane..4*lane+3, head = (4*lane)>>6
    int beg = offs[n], end = offs[n + 1];
    float adn = ad1[(size_t)n * 4 + head];
    float m = -1e30f, ss = 0.f;
    float a0 = 0.f, a1 = 0.f, a2 = 0.f, a3 = 0.f;
    for (int o = beg; o < end; ++o) {
        int s = csr[o];
        float lg = as1[(size_t)s * 4 + head] + adn;
        lg = (lg >= 0.f) ? lg : 0.2f * lg;
        float mn = fmaxf(m, lg);
        float sc = __expf(m - mn);
        float w = __expf(lg - mn);
        m = mn;
        ss = ss * sc + w;
        const float4 hv = *reinterpret_cast<const float4*>(h1 + (size_t)s * 256 + lane * 4);
        a0 = a0 * sc + w * hv.x;
        a1 = a1 * sc + w * hv.y;
        a2 = a2 * sc + w * hv.z;
        a3 = a3 * sc + w * hv.w;
    }
    float inv = 1.f / (ss + 1e-16f);
    const float4 bv = *reinterpret_cast<const float4*>(b1 + lane * 4);
    float o0 = a0 * inv + bv.x;
    float o1 = a1 * inv + bv.y;
    float o2 = a2 * inv + bv.z;
    float o3 = a3 * inv + bv.w;
    o0 = o0 > 0.f ? o0 : expf(o0) - 1.f;
    o1 = o1 > 0.f ? o1 : expf(o1) - 1.f;
    o2 = o2 > 0.f ? o2 : expf(o2) - 1.f;
    o3 = o3 > 0.f ? o3 : expf(o3) - 1.f;
    float4 ov = make_float4(o0, o1, o2, o3);
    *reinterpret_cast<float4*>(x2 + (size_t)n * 256 + lane * 4) = ov;
}

// ---------------------------------------------------------------------------
// GEMM2: h2[r][c] = sum_k x2[r][k] * W2[k][c], k in [0,256), c in [0,64)
// W2 staged in LDS. One wave per row (4 rows per block-iter). Fused att dots.
// ---------------------------------------------------------------------------
__global__ __launch_bounds__(256) void gemm2_kernel(
    const float* __restrict__ x2, int Ntot, const float* __restrict__ W2,
    const float* __restrict__ attS, const float* __restrict__ attD,
    float* __restrict__ h2, float* __restrict__ as2, float* __restrict__ ad2) {
    __shared__ float Wl[256 * 64];
    __shared__ float xr[4][256];
    int t = threadIdx.x;
    for (int i = t; i < 256 * 64; i += 256) Wl[i] = W2[i];
    int lane = t & 63, wv = t >> 6;
    float aS = attS[lane];
    float aD = attD[lane];
    __syncthreads();
    int ntiles = (Ntot + 3) / 4;
    for (int tile = blockIdx.x; tile < ntiles; tile += gridDim.x) {
        int rbase = tile * 4;
        __syncthreads();
        for (int i = t; i < 4 * 256; i += 256) {
            int r = rbase + (i >> 8);
            xr[i >> 8][i & 255] = (r < Ntot) ? x2[(size_t)r * 256 + (i & 255)] : 0.f;
        }
        __syncthreads();
        int r = rbase + wv;
        if (r < Ntot) {
            float acc = 0.f;
#pragma unroll 8
            for (int k = 0; k < 256; ++k) acc += xr[wv][k] * Wl[k * 64 + lane];
            h2[(size_t)r * 64 + lane] = acc;
            float rs = acc * aS, rd = acc * aD;
#pragma unroll
            for (int msk = 32; msk; msk >>= 1) {
                rs += __shfl_xor(rs, msk);
                rd += __shfl_xor(rd, msk);
            }
            if (lane == 0) {
                as2[r] = rs;
                ad2[r] = rd;
            }
        }
    }
}

// ---------------------------------------------------------------------------
// AGG2: per node n, online softmax (1 head, 64 ch), + bias -> d_out
// ---------------------------------------------------------------------------
__global__ __launch_bounds__(256) void agg2_kernel(
    const float* __restrict__ h2, const float* __restrict__ as2,
    const float* __restrict__ ad2, const int* __restrict__ offs,
    const int* __restrict__ csr, const float* __restrict__ b2,
    float* __restrict__ out, int N) {
    int wv = threadIdx.x >> 6, lane = threadIdx.x & 63;
    int n = blockIdx.x * 4 + wv;
    if (n >= N) return;
    int beg = offs[n], end = offs[n + 1];
    float adn = ad2[n];
    float m = -1e30f, ss = 0.f, acc = 0.f;
    for (int o = beg; o < end; ++o) {
        int s = csr[o];
        float lg = as2[s] + adn;
        lg = (lg >= 0.f) ? lg : 0.2f * lg;
        float mn = fmaxf(m, lg);
        float sc = __expf(m - mn);
        float w = __expf(lg - mn);
        m = mn;
        ss = ss * sc + w;
        acc = acc * sc + w * h2[(size_t)s * 64 + lane];
    }
    out[(size_t)n * 64 + lane] = acc / (ss + 1e-16f) + b2[lane];
}

// ---------------------------------------------------------------------------

extern "C" void kernel_launch(void* const* d_in, const int* in_sizes, int n_in,
                              void* d_out, int out_size, void* d_ws, size_t ws_size,
                              hipStream_t stream) {
    const int* ei = (const int*)d_in[0];
    const float* xu = (const float*)d_in[1];
    const float* xi = (const float*)d_in[2];
    const float* W1 = (const float*)d_in[3];
    const float* attS1 = (const float*)d_in[4];
    const float* attD1 = (const float*)d_in[5];
    const float* b1 = (const float*)d_in[6];
    const float* W2 = (const float*)d_in[7];
    const float* attS2 = (const float*)d_in[8];
    const float* attD2 = (const float*)d_in[9];
    const float* b2 = (const float*)d_in[10];
    float* out = (float*)d_out;

    const int E = in_sizes[0] / 2;
    const int NU = in_sizes[1] / 64;
    const int NI = in_sizes[2] / 64;
    const int N = NU + NI;
    const int ET = E + N;

    // --- workspace carve (all offsets 256B-aligned) ---
    char* p = (char*)d_ws;
    auto carve = [&](size_t bytes) {
        void* r = (void*)p;
        p += (bytes + 255) & ~(size_t)255;
        return r;
    };
    float* h1 = (float*)carve((size_t)N * 256 * 4);   // 112.6 MB
    float* x2 = (float*)carve((size_t)N * 256 * 4);   // 112.6 MB
    float* as1 = (float*)carve((size_t)N * 4 * 4);
    float* ad1 = (float*)carve((size_t)N * 4 * 4);
    float* as2 = (float*)carve((size_t)N * 4);
    float* ad2 = (float*)carve((size_t)N * 4);
    int* offs = (int*)carve((size_t)(N + 1) * 4);
    int* cursor = (int*)carve((size_t)N * 4);
    int* csr = (int*)carve((size_t)ET * 4);
    int* bsums = (int*)carve(64 * 4);
    float* h2 = h1;  // h1 dead after agg1; reuse for h2 (N*64 floats)

    // --- build CSR (grouped by dst) ---
    hipMemsetAsync(cursor, 0, (size_t)N * 4, stream);
    {
        int grid = (ET + 255) / 256;
        hist_kernel<<<grid, 256, 0, stream>>>(ei, E, ET, cursor);
    }
    {
        int nsb = (N + 4095) / 4096;
        scan_blocks_kernel<<<nsb, 256, 0, stream>>>(cursor, offs, bsums, N);
        scan_small_kernel<<<1, 64, 0, stream>>>(bsums, nsb);
        int grid = (N + 255) / 256;
        scan_add_kernel<<<grid, 256, 0, stream>>>(offs, bsums, N, ET);
    }
    hipMemcpyAsync(cursor, offs, (size_t)N * 4, hipMemcpyDeviceToDevice, stream);
    {
        int grid = (ET + 255) / 256;
        scatter_kernel<<<grid, 256, 0, stream>>>(ei, E, ET, cursor, csr);
    }

    // --- layer 1 ---
    gemm1_kernel<<<2048, 256, 0, stream>>>(xu, xi, NU, N, W1, attS1, attD1, h1, as1, ad1);
    {
        int grid = (N + 3) / 4;
        agg1_kernel<<<grid, 256, 0, stream>>>(h1, as1, ad1, offs, csr, b1, x2, N);
    }

    // --- layer 2 ---
    gemm2_kernel<<<2048, 256, 0, stream>>>(x2, N, W2, attS2, attD2, h2, as2, ad2);
    {
        int grid = (N + 3) / 4;
        agg2_kernel<<<grid, 256, 0, stream>>>(h2, as2, ad2, offs, csr, b2, out, N);
    }
}

// Round 2
// 458.163 us; speedup vs baseline: 1.7285x; 1.7285x over previous
//
#include <hip/hip_runtime.h>
#include <math.h>

// ---------------------------------------------------------------------------
// GATRec: 2-layer GAT on 110k nodes, 1M edges (+N self loops).
// build CSR -> gemm1(MFMA bf16)+att -> agg1(softmax+ELU, bf16 gather)
//           -> gemm2(MFMA bf16)+att -> agg2 -> d_out (f32)
// ---------------------------------------------------------------------------

typedef float f32x4 __attribute__((ext_vector_type(4)));
typedef short s16x8 __attribute__((ext_vector_type(8)));

static __device__ __forceinline__ short f2bf(float f) {
    unsigned u = __builtin_bit_cast(unsigned, f);
    u = (u + 0x7fff + ((u >> 16) & 1)) >> 16;  // RNE
    return (short)u;
}
static __device__ __forceinline__ float bf2f(unsigned short u) {
    unsigned v = ((unsigned)u) << 16;
    return __builtin_bit_cast(float, v);
}

// ------------------------------- graph build -------------------------------

__global__ void hist_kernel(const int* __restrict__ ei, int E, int ET,
                            int* __restrict__ cnt) {
    int e = blockIdx.x * blockDim.x + threadIdx.x;
    if (e >= ET) return;
    int d = (e < E) ? ei[E + e] : (e - E);
    atomicAdd(&cnt[d], 1);
}

__global__ __launch_bounds__(256) void scan_blocks_kernel(
    const int* __restrict__ cnt, int* __restrict__ offs,
    int* __restrict__ bsums, int n) {
    __shared__ int sdata[256];
    int base = blockIdx.x * 4096 + threadIdx.x * 16;
    int vals[16];
    int tsum = 0;
#pragma unroll
    for (int i = 0; i < 16; ++i) {
        int idx = base + i;
        int v = (idx < n) ? cnt[idx] : 0;
        vals[i] = v;
        tsum += v;
    }
    sdata[threadIdx.x] = tsum;
    __syncthreads();
    for (int off = 1; off < 256; off <<= 1) {
        int v = (threadIdx.x >= off) ? sdata[threadIdx.x - off] : 0;
        __syncthreads();
        sdata[threadIdx.x] += v;
        __syncthreads();
    }
    int run = sdata[threadIdx.x] - tsum;
    if (threadIdx.x == 255) bsums[blockIdx.x] = sdata[255];
#pragma unroll
    for (int i = 0; i < 16; ++i) {
        int idx = base + i;
        if (idx < n) offs[idx] = run;
        run += vals[i];
    }
}

__global__ void scan_small_kernel(int* bsums, int nb) {
    if (blockIdx.x == 0 && threadIdx.x == 0) {
        int run = 0;
        for (int i = 0; i < nb; ++i) {
            int v = bsums[i];
            bsums[i] = run;
            run += v;
        }
    }
}

__global__ void scan_add_kernel(int* __restrict__ offs,
                                const int* __restrict__ bsums, int n, int total) {
    int idx = blockIdx.x * blockDim.x + threadIdx.x;
    if (idx < n) offs[idx] += bsums[idx >> 12];
    if (idx == 0) offs[n] = total;
}

__global__ void scatter_kernel(const int* __restrict__ ei, int E, int ET,
                               int* __restrict__ cursor, int* __restrict__ csr) {
    int e = blockIdx.x * blockDim.x + threadIdx.x;
    if (e >= ET) return;
    int s, d;
    if (e < E) { s = ei[e]; d = ei[E + e]; } else { s = e - E; d = e - E; }
    int pos = atomicAdd(&cursor[d], 1);
    csr[pos] = s;
}

// ---------------------------------------------------------------------------
// GEMM1 (MFMA): h1[N,256] = x[N,64] @ W1[64,256], bf16 out, fused att dots.
// Wave owns 16 rows x 256 cols: 16 col-frags x 2 K-steps = 32 MFMAs.
// B (all of W1) pre-packed in 32 frags = 128 VGPR, loaded once per wave.
// ---------------------------------------------------------------------------
__global__ __launch_bounds__(256, 1) void gemm1_mfma(
    const float* __restrict__ xu, const float* __restrict__ xi, int NU, int N,
    const float* __restrict__ W1, const float* __restrict__ attS,
    const float* __restrict__ attD, unsigned short* __restrict__ h1,
    float* __restrict__ as1, float* __restrict__ ad1) {
    int t = threadIdx.x;
    int wv = t >> 6;
    int l = t & 63;
    int l15 = l & 15;
    int lg = l >> 4;

    // B fragments: lane l holds B[k=8*lg+j][col=ct*16+l15], k within K-step ks
    s16x8 Bfr[16][2];
#pragma unroll
    for (int ct = 0; ct < 16; ++ct)
#pragma unroll
        for (int ks = 0; ks < 2; ++ks) {
            s16x8 f;
#pragma unroll
            for (int j = 0; j < 8; ++j)
                f[j] = f2bf(W1[(size_t)(ks * 32 + lg * 8 + j) * 256 + ct * 16 + l15]);
            Bfr[ct][ks] = f;
        }
    float attSv[16], attDv[16];
#pragma unroll
    for (int ct = 0; ct < 16; ++ct) {
        attSv[ct] = attS[ct * 16 + l15];
        attDv[ct] = attD[ct * 16 + l15];
    }

    int wid = blockIdx.x * 4 + wv;
    int ntile = (N + 15) >> 4;
    int stride = gridDim.x * 4;
    for (int tile = wid; tile < ntile; tile += stride) {
        int rbase = tile * 16;
        // A fragments: lane l holds A[row=l15][k=8*lg+j]
        int arow = rbase + l15;
        if (arow >= N) arow = N - 1;
        const float* xp = (arow < NU) ? (xu + (size_t)arow * 64)
                                      : (xi + (size_t)(arow - NU) * 64);
        s16x8 Afr[2];
#pragma unroll
        for (int ks = 0; ks < 2; ++ks) {
            const float4* p = reinterpret_cast<const float4*>(xp + ks * 32 + lg * 8);
            float4 v0 = p[0];
            float4 v1 = p[1];
            s16x8 f;
            f[0] = f2bf(v0.x); f[1] = f2bf(v0.y); f[2] = f2bf(v0.z); f[3] = f2bf(v0.w);
            f[4] = f2bf(v1.x); f[5] = f2bf(v1.y); f[6] = f2bf(v1.z); f[7] = f2bf(v1.w);
            Afr[ks] = f;
        }
        f32x4 acc[16];
#pragma unroll
        for (int ct = 0; ct < 16; ++ct) acc[ct] = (f32x4){0.f, 0.f, 0.f, 0.f};
#pragma unroll
        for (int ct = 0; ct < 16; ++ct) {
            acc[ct] = __builtin_amdgcn_mfma_f32_16x16x32_bf16(Afr[0], Bfr[ct][0], acc[ct], 0, 0, 0);
            acc[ct] = __builtin_amdgcn_mfma_f32_16x16x32_bf16(Afr[1], Bfr[ct][1], acc[ct], 0, 0, 0);
        }
        // D layout: row = rbase + lg*4 + i, col = ct*16 + l15
        int r0 = rbase + lg * 4;
        // attention dots per head
#pragma unroll
        for (int h = 0; h < 4; ++h) {
#pragma unroll
            for (int i = 0; i < 4; ++i) {
                float rs = acc[4 * h + 0][i] * attSv[4 * h + 0] + acc[4 * h + 1][i] * attSv[4 * h + 1]
                         + acc[4 * h + 2][i] * attSv[4 * h + 2] + acc[4 * h + 3][i] * attSv[4 * h + 3];
                float rd = acc[4 * h + 0][i] * attDv[4 * h + 0] + acc[4 * h + 1][i] * attDv[4 * h + 1]
                         + acc[4 * h + 2][i] * attDv[4 * h + 2] + acc[4 * h + 3][i] * attDv[4 * h + 3];
#pragma unroll
                for (int msk = 8; msk; msk >>= 1) {
                    rs += __shfl_xor(rs, msk);
                    rd += __shfl_xor(rd, msk);
                }
                int r = r0 + i;
                if (l15 == 0 && r < N) {
                    as1[(size_t)r * 4 + h] = rs;
                    ad1[(size_t)r * 4 + h] = rd;
                }
            }
        }
        // h1 bf16 stores
#pragma unroll
        for (int ct = 0; ct < 16; ++ct)
#pragma unroll
            for (int i = 0; i < 4; ++i) {
                int r = r0 + i;
                if (r < N)
                    h1[(size_t)r * 256 + ct * 16 + l15] = (unsigned short)f2bf(acc[ct][i]);
            }
    }
}

// ---------------------------------------------------------------------------
// AGG1: per node, online softmax over incoming edges (4 heads), bf16 gather,
// + bias, ELU, write x2 bf16. One wave/node, lane owns 4 channels.
// ---------------------------------------------------------------------------
__global__ __launch_bounds__(256) void agg1_kernel(
    const unsigned short* __restrict__ h1, const float* __restrict__ as1,
    const float* __restrict__ ad1, const int* __restrict__ offs,
    const int* __restrict__ csr, const float* __restrict__ b1,
    unsigned short* __restrict__ x2, int N) {
    int wv = threadIdx.x >> 6, lane = threadIdx.x & 63;
    int n = blockIdx.x * 4 + wv;
    if (n >= N) return;
    int head = lane >> 4;
    int beg = offs[n], end = offs[n + 1];
    float adn = ad1[(size_t)n * 4 + head];
    float m = -1e30f, ss = 0.f;
    float a0 = 0.f, a1 = 0.f, a2 = 0.f, a3 = 0.f;

    int sC = csr[beg];
    float lgC = as1[(size_t)sC * 4 + head];
    ushort4 hvC = *reinterpret_cast<const ushort4*>(h1 + (size_t)sC * 256 + lane * 4);
    for (int o = beg; o < end; ++o) {
        int oN = o + 1 < end ? o + 1 : o;
        int sN = csr[oN];
        float lgN = as1[(size_t)sN * 4 + head];
        ushort4 hvN = *reinterpret_cast<const ushort4*>(h1 + (size_t)sN * 256 + lane * 4);
        float lg = lgC + adn;
        lg = (lg >= 0.f) ? lg : 0.2f * lg;
        float mn = fmaxf(m, lg);
        float sc = __expf(m - mn);
        float w = __expf(lg - mn);
        m = mn;
        ss = ss * sc + w;
        a0 = a0 * sc + w * bf2f(hvC.x);
        a1 = a1 * sc + w * bf2f(hvC.y);
        a2 = a2 * sc + w * bf2f(hvC.z);
        a3 = a3 * sc + w * bf2f(hvC.w);
        lgC = lgN;
        hvC = hvN;
    }
    float inv = 1.f / (ss + 1e-16f);
    const float4 bv = *reinterpret_cast<const float4*>(b1 + lane * 4);
    float o0 = a0 * inv + bv.x;
    float o1 = a1 * inv + bv.y;
    float o2 = a2 * inv + bv.z;
    float o3 = a3 * inv + bv.w;
    o0 = o0 > 0.f ? o0 : expf(o0) - 1.f;
    o1 = o1 > 0.f ? o1 : expf(o1) - 1.f;
    o2 = o2 > 0.f ? o2 : expf(o2) - 1.f;
    o3 = o3 > 0.f ? o3 : expf(o3) - 1.f;
    ushort4 ov;
    ov.x = (unsigned short)f2bf(o0);
    ov.y = (unsigned short)f2bf(o1);
    ov.z = (unsigned short)f2bf(o2);
    ov.w = (unsigned short)f2bf(o3);
    *reinterpret_cast<ushort4*>(x2 + (size_t)n * 256 + lane * 4) = ov;
}

// ---------------------------------------------------------------------------
// GEMM2 (MFMA): h2[N,64] = x2[N,256] @ W2[256,64], bf16 in/out, fused att.
// Wave owns 16 rows x 64 cols: 4 col-frags x 8 K-steps = 32 MFMAs.
// ---------------------------------------------------------------------------
__global__ __launch_bounds__(256, 2) void gemm2_mfma(
    const unsigned short* __restrict__ x2, int N, const float* __restrict__ W2,
    const float* __restrict__ attS, const float* __restrict__ attD,
    unsigned short* __restrict__ h2, float* __restrict__ as2,
    float* __restrict__ ad2) {
    int t = threadIdx.x;
    int wv = t >> 6;
    int l = t & 63;
    int l15 = l & 15;
    int lg = l >> 4;

    s16x8 Bfr[8][4];
#pragma unroll
    for (int ks = 0; ks < 8; ++ks)
#pragma unroll
        for (int ct = 0; ct < 4; ++ct) {
            s16x8 f;
#pragma unroll
            for (int j = 0; j < 8; ++j)
                f[j] = f2bf(W2[(size_t)(ks * 32 + lg * 8 + j) * 64 + ct * 16 + l15]);
            Bfr[ks][ct] = f;
        }
    float attSv[4], attDv[4];
#pragma unroll
    for (int ct = 0; ct < 4; ++ct) {
        attSv[ct] = attS[ct * 16 + l15];
        attDv[ct] = attD[ct * 16 + l15];
    }

    int wid = blockIdx.x * 4 + wv;
    int ntile = (N + 15) >> 4;
    int stride = gridDim.x * 4;
    for (int tile = wid; tile < ntile; tile += stride) {
        int rbase = tile * 16;
        int arow = rbase + l15;
        if (arow >= N) arow = N - 1;
        const unsigned short* xp = x2 + (size_t)arow * 256;
        f32x4 acc[4];
#pragma unroll
        for (int ct = 0; ct < 4; ++ct) acc[ct] = (f32x4){0.f, 0.f, 0.f, 0.f};
#pragma unroll
        for (int ks = 0; ks < 8; ++ks) {
            s16x8 Afr = *reinterpret_cast<const s16x8*>(xp + ks * 32 + lg * 8);
#pragma unroll
            for (int ct = 0; ct < 4; ++ct)
                acc[ct] = __builtin_amdgcn_mfma_f32_16x16x32_bf16(Afr, Bfr[ks][ct], acc[ct], 0, 0, 0);
        }
        int r0 = rbase + lg * 4;
#pragma unroll
        for (int i = 0; i < 4; ++i) {
            float rs = acc[0][i] * attSv[0] + acc[1][i] * attSv[1]
                     + acc[2][i] * attSv[2] + acc[3][i] * attSv[3];
            float rd = acc[0][i] * attDv[0] + acc[1][i] * attDv[1]
                     + acc[2][i] * attDv[2] + acc[3][i] * attDv[3];
#pragma unroll
            for (int msk = 8; msk; msk >>= 1) {
                rs += __shfl_xor(rs, msk);
                rd += __shfl_xor(rd, msk);
            }
            int r = r0 + i;
            if (l15 == 0 && r < N) {
                as2[r] = rs;
                ad2[r] = rd;
            }
        }
#pragma unroll
        for (int ct = 0; ct < 4; ++ct)
#pragma unroll
            for (int i = 0; i < 4; ++i) {
                int r = r0 + i;
                if (r < N)
                    h2[(size_t)r * 64 + ct * 16 + l15] = (unsigned short)f2bf(acc[ct][i]);
            }
    }
}

// ---------------------------------------------------------------------------
// AGG2: per node, online softmax (1 head, 64 ch), bf16 gather, + bias -> out
// ---------------------------------------------------------------------------
__global__ __launch_bounds__(256) void agg2_kernel(
    const unsigned short* __restrict__ h2, const float* __restrict__ as2,
    const float* __restrict__ ad2, const int* __restrict__ offs,
    const int* __restrict__ csr, const float* __restrict__ b2,
    float* __restrict__ out, int N) {
    int wv = threadIdx.x >> 6, lane = threadIdx.x & 63;
    int n = blockIdx.x * 4 + wv;
    if (n >= N) return;
    int beg = offs[n], end = offs[n + 1];
    float adn = ad2[n];
    float m = -1e30f, ss = 0.f, acc = 0.f;

    int sC = csr[beg];
    float lgC = as2[sC];
    unsigned short hvC = h2[(size_t)sC * 64 + lane];
    for (int o = beg; o < end; ++o) {
        int oN = o + 1 < end ? o + 1 : o;
        int sN = csr[oN];
        float lgN = as2[sN];
        unsigned short hvN = h2[(size_t)sN * 64 + lane];
        float lg = lgC + adn;
        lg = (lg >= 0.f) ? lg : 0.2f * lg;
        float mn = fmaxf(m, lg);
        float sc = __expf(m - mn);
        float w = __expf(lg - mn);
        m = mn;
        ss = ss * sc + w;
        acc = acc * sc + w * bf2f(hvC);
        lgC = lgN;
        hvC = hvN;
    }
    out[(size_t)n * 64 + lane] = acc / (ss + 1e-16f) + b2[lane];
}

// ---------------------------------------------------------------------------

extern "C" void kernel_launch(void* const* d_in, const int* in_sizes, int n_in,
                              void* d_out, int out_size, void* d_ws, size_t ws_size,
                              hipStream_t stream) {
    const int* ei = (const int*)d_in[0];
    const float* xu = (const float*)d_in[1];
    const float* xi = (const float*)d_in[2];
    const float* W1 = (const float*)d_in[3];
    const float* attS1 = (const float*)d_in[4];
    const float* attD1 = (const float*)d_in[5];
    const float* b1 = (const float*)d_in[6];
    const float* W2 = (const float*)d_in[7];
    const float* attS2 = (const float*)d_in[8];
    const float* attD2 = (const float*)d_in[9];
    const float* b2 = (const float*)d_in[10];
    float* out = (float*)d_out;

    const int E = in_sizes[0] / 2;
    const int NU = in_sizes[1] / 64;
    const int NI = in_sizes[2] / 64;
    const int N = NU + NI;
    const int ET = E + N;

    char* p = (char*)d_ws;
    auto carve = [&](size_t bytes) {
        void* r = (void*)p;
        p += (bytes + 255) & ~(size_t)255;
        return r;
    };
    unsigned short* h1 = (unsigned short*)carve((size_t)N * 256 * 2);  // 56.3 MB
    unsigned short* x2 = (unsigned short*)carve((size_t)N * 256 * 2);  // 56.3 MB
    float* as1 = (float*)carve((size_t)N * 4 * 4);
    float* ad1 = (float*)carve((size_t)N * 4 * 4);
    float* as2 = (float*)carve((size_t)N * 4);
    float* ad2 = (float*)carve((size_t)N * 4);
    int* offs = (int*)carve((size_t)(N + 1) * 4);
    int* cursor = (int*)carve((size_t)N * 4);
    int* csr = (int*)carve((size_t)ET * 4);
    int* bsums = (int*)carve(64 * 4);
    unsigned short* h2 = h1;  // h1 dead after agg1

    // --- build CSR (grouped by dst) ---
    hipMemsetAsync(cursor, 0, (size_t)N * 4, stream);
    {
        int grid = (ET + 255) / 256;
        hist_kernel<<<grid, 256, 0, stream>>>(ei, E, ET, cursor);
    }
    {
        int nsb = (N + 4095) / 4096;
        scan_blocks_kernel<<<nsb, 256, 0, stream>>>(cursor, offs, bsums, N);
        scan_small_kernel<<<1, 64, 0, stream>>>(bsums, nsb);
        int grid = (N + 255) / 256;
        scan_add_kernel<<<grid, 256, 0, stream>>>(offs, bsums, N, ET);
    }
    hipMemcpyAsync(cursor, offs, (size_t)N * 4, hipMemcpyDeviceToDevice, stream);
    {
        int grid = (ET + 255) / 256;
        scatter_kernel<<<grid, 256, 0, stream>>>(ei, E, ET, cursor, csr);
    }

    // --- layer 1 ---
    gemm1_mfma<<<512, 256, 0, stream>>>(xu, xi, NU, N, W1, attS1, attD1, h1, as1, ad1);
    agg1_kernel<<<(N + 3) / 4, 256, 0, stream>>>(h1, as1, ad1, offs, csr, b1, x2, N);

    // --- layer 2 ---
    gemm2_mfma<<<512, 256, 0, stream>>>(x2, N, W2, attS2, attD2, h2, as2, ad2);
    agg2_kernel<<<(N + 3) / 4, 256, 0, stream>>>(h2, as2, ad2, offs, csr, b2, out, N);
}

// Round 3
// 422.618 us; speedup vs baseline: 1.8738x; 1.0841x over previous
//
#include <hip/hip_runtime.h>
#include <math.h>

// ---------------------------------------------------------------------------
// GATRec restructured:
//   a_src = h·attS = x·(W@attS)  -> logits computed from x directly
//   out   = sum(alpha * (x@W))   = (sum(alpha * x)) @ W   (aggregate first!)
// Layer 1: gather x (bf16, 14MB, L2-resident) -> y[N,4,64] -> GEMM(W1)+ELU
// Layer 2: gather h2 (bf16, 14MB, L2-resident), h2 = x2@W2
// No-max softmax (logits ~ +-0.2): ss += w; acc += w*h  (no rescale chain)
// ---------------------------------------------------------------------------

typedef float f32x4 __attribute__((ext_vector_type(4)));
typedef short s16x8 __attribute__((ext_vector_type(8)));

static __device__ __forceinline__ short f2bf(float f) {
    unsigned u = __builtin_bit_cast(unsigned, f);
    u = (u + 0x7fff + ((u >> 16) & 1)) >> 16;  // RNE
    return (short)u;
}
static __device__ __forceinline__ float bf2f(unsigned short u) {
    unsigned v = ((unsigned)u) << 16;
    return __builtin_bit_cast(float, v);
}

// ------------------------------- graph build -------------------------------

__global__ void hist_kernel(const int* __restrict__ ei, int E, int ET,
                            int* __restrict__ cnt) {
    int e = blockIdx.x * blockDim.x + threadIdx.x;
    if (e >= ET) return;
    int d = (e < E) ? ei[E + e] : (e - E);
    atomicAdd(&cnt[d], 1);
}

__global__ __launch_bounds__(256) void scan_blocks_kernel(
    const int* __restrict__ cnt, int* __restrict__ offs,
    int* __restrict__ bsums, int n) {
    __shared__ int sdata[256];
    int base = blockIdx.x * 4096 + threadIdx.x * 16;
    int vals[16];
    int tsum = 0;
#pragma unroll
    for (int i = 0; i < 16; ++i) {
        int idx = base + i;
        int v = (idx < n) ? cnt[idx] : 0;
        vals[i] = v;
        tsum += v;
    }
    sdata[threadIdx.x] = tsum;
    __syncthreads();
    for (int off = 1; off < 256; off <<= 1) {
        int v = (threadIdx.x >= off) ? sdata[threadIdx.x - off] : 0;
        __syncthreads();
        sdata[threadIdx.x] += v;
        __syncthreads();
    }
    int run = sdata[threadIdx.x] - tsum;
    if (threadIdx.x == 255) bsums[blockIdx.x] = sdata[255];
#pragma unroll
    for (int i = 0; i < 16; ++i) {
        int idx = base + i;
        if (idx < n) offs[idx] = run;
        run += vals[i];
    }
}

__global__ void scan_small_kernel(int* bsums, int nb) {
    if (blockIdx.x == 0 && threadIdx.x == 0) {
        int run = 0;
        for (int i = 0; i < nb; ++i) {
            int v = bsums[i];
            bsums[i] = run;
            run += v;
        }
    }
}

__global__ void scan_add_kernel(int* __restrict__ offs,
                                const int* __restrict__ bsums, int n, int total) {
    int idx = blockIdx.x * blockDim.x + threadIdx.x;
    if (idx < n) offs[idx] += bsums[idx >> 12];
    if (idx == 0) offs[n] = total;
}

__global__ void scatter_kernel(const int* __restrict__ ei, int E, int ET,
                               int* __restrict__ cursor, int* __restrict__ csr) {
    int e = blockIdx.x * blockDim.x + threadIdx.x;
    if (e >= ET) return;
    int s, d;
    if (e < E) { s = ei[e]; d = ei[E + e]; } else { s = e - E; d = e - E; }
    int pos = atomicAdd(&cursor[d], 1);
    csr[pos] = s;
}

// ---------------------------------------------------------------------------
// prep_attv: attv1s[k][h] = sum_c W1[k][h*64+c]*attS1[h][c]   (64x4)
//            attv2s[k]    = sum_c W2[k][c]*attS2[c]           (256)
// ---------------------------------------------------------------------------
__global__ void prep_attv_kernel(const float* __restrict__ W1,
                                 const float* __restrict__ attS1,
                                 const float* __restrict__ attD1,
                                 const float* __restrict__ W2,
                                 const float* __restrict__ attS2,
                                 const float* __restrict__ attD2,
                                 float* __restrict__ attv1s, float* __restrict__ attv1d,
                                 float* __restrict__ attv2s, float* __restrict__ attv2d) {
    int t = threadIdx.x;
    {
        int k = t >> 2, h = t & 3;
        float ss = 0.f, sd = 0.f;
        for (int c = 0; c < 64; ++c) {
            float w = W1[k * 256 + h * 64 + c];
            ss += w * attS1[h * 64 + c];
            sd += w * attD1[h * 64 + c];
        }
        attv1s[k * 4 + h] = ss;
        attv1d[k * 4 + h] = sd;
    }
    {
        float ss = 0.f, sd = 0.f;
        for (int c = 0; c < 64; ++c) {
            float w = W2[t * 64 + c];
            ss += w * attS2[c];
            sd += w * attD2[c];
        }
        attv2s[t] = ss;
        attv2d[t] = sd;
    }
}

// ---------------------------------------------------------------------------
// cast_att: xb[n][64] = bf16(x[n]); as1[n][h] = x[n]·attv1s[:,h]; same ad1.
// One wave per row, lane = channel.
// ---------------------------------------------------------------------------
__global__ __launch_bounds__(256) void cast_att_kernel(
    const float* __restrict__ xu, const float* __restrict__ xi, int NU, int N,
    const float* __restrict__ attv1s, const float* __restrict__ attv1d,
    unsigned short* __restrict__ xb, float* __restrict__ as1,
    float* __restrict__ ad1) {
    int wv = threadIdx.x >> 6, lane = threadIdx.x & 63;
    int n = blockIdx.x * 4 + wv;
    if (n >= N) return;
    float v = (n < NU) ? xu[(size_t)n * 64 + lane] : xi[(size_t)(n - NU) * 64 + lane];
    xb[(size_t)n * 64 + lane] = (unsigned short)f2bf(v);
    float4 avS = *reinterpret_cast<const float4*>(attv1s + lane * 4);
    float4 avD = *reinterpret_cast<const float4*>(attv1d + lane * 4);
    float s0 = v * avS.x, s1 = v * avS.y, s2 = v * avS.z, s3 = v * avS.w;
    float d0 = v * avD.x, d1 = v * avD.y, d2 = v * avD.z, d3 = v * avD.w;
#pragma unroll
    for (int msk = 32; msk; msk >>= 1) {
        s0 += __shfl_xor(s0, msk); s1 += __shfl_xor(s1, msk);
        s2 += __shfl_xor(s2, msk); s3 += __shfl_xor(s3, msk);
        d0 += __shfl_xor(d0, msk); d1 += __shfl_xor(d1, msk);
        d2 += __shfl_xor(d2, msk); d3 += __shfl_xor(d3, msk);
    }
    if (lane == 0) {
        *reinterpret_cast<float4*>(as1 + (size_t)n * 4) = make_float4(s0, s1, s2, s3);
        *reinterpret_cast<float4*>(ad1 + (size_t)n * 4) = make_float4(d0, d1, d2, d3);
    }
}

// ---------------------------------------------------------------------------
// AGG1: y[n][h][c] = sum_e alpha_eh * x[src_e][c]   (no-max softmax)
// Wave per node; lane owns (h = lane>>4, 4 in-channels). bf16 out.
// ---------------------------------------------------------------------------
__global__ __launch_bounds__(256) void agg1_kernel(
    const unsigned short* __restrict__ xb, const float* __restrict__ as1,
    const float* __restrict__ ad1, const int* __restrict__ offs,
    const int* __restrict__ csr, unsigned short* __restrict__ yb, int N) {
    int wv = threadIdx.x >> 6, lane = threadIdx.x & 63;
    int n = blockIdx.x * 4 + wv;
    if (n >= N) return;
    int h = lane >> 4, c4 = (lane & 15) * 4;
    int beg = offs[n], end = offs[n + 1];
    float adn = ad1[(size_t)n * 4 + h];
    float ss = 0.f, a0 = 0.f, a1 = 0.f, a2 = 0.f, a3 = 0.f;

    int sA = csr[beg];
    float lgA = as1[(size_t)sA * 4 + h];
    ushort4 hA = *reinterpret_cast<const ushort4*>(xb + (size_t)sA * 64 + c4);
    int o1 = (beg + 1 < end) ? beg + 1 : beg;
    int sB = csr[o1];
    float lgB = as1[(size_t)sB * 4 + h];
    ushort4 hB = *reinterpret_cast<const ushort4*>(xb + (size_t)sB * 64 + c4);

    for (int o = beg; o < end; ++o) {
        int op = o + 2;
        int sP = (op < end) ? csr[op] : sA;
        float lgP = as1[(size_t)sP * 4 + h];
        ushort4 hP = *reinterpret_cast<const ushort4*>(xb + (size_t)sP * 64 + c4);
        float lg = lgA + adn;
        lg = (lg >= 0.f) ? lg : 0.2f * lg;
        float w = __expf(lg);
        ss += w;
        a0 += w * bf2f(hA.x);
        a1 += w * bf2f(hA.y);
        a2 += w * bf2f(hA.z);
        a3 += w * bf2f(hA.w);
        lgA = lgB; hA = hB;
        lgB = lgP; hB = hP;
    }
    float inv = 1.f / (ss + 1e-16f);
    ushort4 ov;
    ov.x = (unsigned short)f2bf(a0 * inv);
    ov.y = (unsigned short)f2bf(a1 * inv);
    ov.z = (unsigned short)f2bf(a2 * inv);
    ov.w = (unsigned short)f2bf(a3 * inv);
    *reinterpret_cast<ushort4*>(yb + (size_t)n * 256 + h * 64 + c4) = ov;
}

// ---------------------------------------------------------------------------
// GEMM-mid (MFMA): x2[n][j] = ELU( y[n][head(j)][:] · W1[:][j] + b1[j] )
// Fused epilogue: as2[n] = x2[n]·attv2s, ad2[n] = x2[n]·attv2d.
// Wave: 16 rows x 256 cols. A-frags head-dependent.
// ---------------------------------------------------------------------------
__global__ __launch_bounds__(256, 1) void gemm_mid_mfma(
    const unsigned short* __restrict__ yb, int N, const float* __restrict__ W1,
    const float* __restrict__ b1, const float* __restrict__ attv2s,
    const float* __restrict__ attv2d, unsigned short* __restrict__ x2,
    float* __restrict__ as2, float* __restrict__ ad2) {
    int t = threadIdx.x;
    int wv = t >> 6;
    int l = t & 63;
    int l15 = l & 15;
    int lg = l >> 4;

    s16x8 Bfr[16][2];
#pragma unroll
    for (int ct = 0; ct < 16; ++ct)
#pragma unroll
        for (int ks = 0; ks < 2; ++ks) {
            s16x8 f;
#pragma unroll
            for (int j = 0; j < 8; ++j)
                f[j] = f2bf(W1[(size_t)(ks * 32 + lg * 8 + j) * 256 + ct * 16 + l15]);
            Bfr[ct][ks] = f;
        }

    int wid = blockIdx.x * 4 + wv;
    int ntile = (N + 15) >> 4;
    int stride = gridDim.x * 4;
    for (int tile = wid; tile < ntile; tile += stride) {
        int rbase = tile * 16;
        int arow = rbase + l15;
        if (arow >= N) arow = N - 1;
        const unsigned short* yp = yb + (size_t)arow * 256;
        s16x8 Afr[4][2];
#pragma unroll
        for (int hd = 0; hd < 4; ++hd)
#pragma unroll
            for (int ks = 0; ks < 2; ++ks)
                Afr[hd][ks] = *reinterpret_cast<const s16x8*>(yp + hd * 64 + ks * 32 + lg * 8);
        f32x4 acc[16];
#pragma unroll
        for (int ct = 0; ct < 16; ++ct) acc[ct] = (f32x4){0.f, 0.f, 0.f, 0.f};
#pragma unroll
        for (int ct = 0; ct < 16; ++ct) {
            int hd = ct >> 2;
            acc[ct] = __builtin_amdgcn_mfma_f32_16x16x32_bf16(Afr[hd][0], Bfr[ct][0], acc[ct], 0, 0, 0);
            acc[ct] = __builtin_amdgcn_mfma_f32_16x16x32_bf16(Afr[hd][1], Bfr[ct][1], acc[ct], 0, 0, 0);
        }
        // epilogue: bias + ELU + store x2, att dots
        int r0 = rbase + lg * 4;
        float rs[4] = {0.f, 0.f, 0.f, 0.f};
        float rd[4] = {0.f, 0.f, 0.f, 0.f};
#pragma unroll
        for (int ct = 0; ct < 16; ++ct) {
            int col = ct * 16 + l15;
            float bv = b1[col];
            float avs = attv2s[col];
            float avd = attv2d[col];
#pragma unroll
            for (int i = 0; i < 4; ++i) {
                float v = acc[ct][i] + bv;
                v = (v > 0.f) ? v : __expf(v) - 1.f;
                rs[i] += v * avs;
                rd[i] += v * avd;
                int r = r0 + i;
                if (r < N)
                    x2[(size_t)r * 256 + col] = (unsigned short)f2bf(v);
            }
        }
#pragma unroll
        for (int i = 0; i < 4; ++i) {
#pragma unroll
            for (int msk = 8; msk; msk >>= 1) {
                rs[i] += __shfl_xor(rs[i], msk);
                rd[i] += __shfl_xor(rd[i], msk);
            }
            int r = r0 + i;
            if (l15 == 0 && r < N) {
                as2[r] = rs[i];
                ad2[r] = rd[i];
            }
        }
    }
}

// ---------------------------------------------------------------------------
// GEMM2 (MFMA): h2[N,64] = x2[N,256] @ W2[256,64], bf16 in/out.
// ---------------------------------------------------------------------------
__global__ __launch_bounds__(256, 2) void gemm2_mfma(
    const unsigned short* __restrict__ x2, int N, const float* __restrict__ W2,
    unsigned short* __restrict__ h2) {
    int t = threadIdx.x;
    int wv = t >> 6;
    int l = t & 63;
    int l15 = l & 15;
    int lg = l >> 4;

    s16x8 Bfr[8][4];
#pragma unroll
    for (int ks = 0; ks < 8; ++ks)
#pragma unroll
        for (int ct = 0; ct < 4; ++ct) {
            s16x8 f;
#pragma unroll
            for (int j = 0; j < 8; ++j)
                f[j] = f2bf(W2[(size_t)(ks * 32 + lg * 8 + j) * 64 + ct * 16 + l15]);
            Bfr[ks][ct] = f;
        }

    int wid = blockIdx.x * 4 + wv;
    int ntile = (N + 15) >> 4;
    int stride = gridDim.x * 4;
    for (int tile = wid; tile < ntile; tile += stride) {
        int rbase = tile * 16;
        int arow = rbase + l15;
        if (arow >= N) arow = N - 1;
        const unsigned short* xp = x2 + (size_t)arow * 256;
        f32x4 acc[4];
#pragma unroll
        for (int ct = 0; ct < 4; ++ct) acc[ct] = (f32x4){0.f, 0.f, 0.f, 0.f};
#pragma unroll
        for (int ks = 0; ks < 8; ++ks) {
            s16x8 Afr = *reinterpret_cast<const s16x8*>(xp + ks * 32 + lg * 8);
#pragma unroll
            for (int ct = 0; ct < 4; ++ct)
                acc[ct] = __builtin_amdgcn_mfma_f32_16x16x32_bf16(Afr, Bfr[ks][ct], acc[ct], 0, 0, 0);
        }
        int r0 = rbase + lg * 4;
#pragma unroll
        for (int ct = 0; ct < 4; ++ct)
#pragma unroll
            for (int i = 0; i < 4; ++i) {
                int r = r0 + i;
                if (r < N)
                    h2[(size_t)r * 64 + ct * 16 + l15] = (unsigned short)f2bf(acc[ct][i]);
            }
    }
}

// ---------------------------------------------------------------------------
// AGG2: out[n] = sum_e alpha_e * h2[src_e] + b2  (no-max softmax), f32 out.
// ---------------------------------------------------------------------------
__global__ __launch_bounds__(256) void agg2_kernel(
    const unsigned short* __restrict__ h2, const float* __restrict__ as2,
    const float* __restrict__ ad2, const int* __restrict__ offs,
    const int* __restrict__ csr, const float* __restrict__ b2,
    float* __restrict__ out, int N) {
    int wv = threadIdx.x >> 6, lane = threadIdx.x & 63;
    int n = blockIdx.x * 4 + wv;
    if (n >= N) return;
    int beg = offs[n], end = offs[n + 1];
    float adn = ad2[n];
    float ss = 0.f, acc = 0.f;

    int sA = csr[beg];
    float lgA = as2[sA];
    unsigned short hA = h2[(size_t)sA * 64 + lane];
    int o1 = (beg + 1 < end) ? beg + 1 : beg;
    int sB = csr[o1];
    float lgB = as2[sB];
    unsigned short hB = h2[(size_t)sB * 64 + lane];

    for (int o = beg; o < end; ++o) {
        int op = o + 2;
        int sP = (op < end) ? csr[op] : sA;
        float lgP = as2[sP];
        unsigned short hP = h2[(size_t)sP * 64 + lane];
        float lg = lgA + adn;
        lg = (lg >= 0.f) ? lg : 0.2f * lg;
        float w = __expf(lg);
        ss += w;
        acc += w * bf2f(hA);
        lgA = lgB; hA = hB;
        lgB = lgP; hB = hP;
    }
    out[(size_t)n * 64 + lane] = acc / (ss + 1e-16f) + b2[lane];
}

// ---------------------------------------------------------------------------

extern "C" void kernel_launch(void* const* d_in, const int* in_sizes, int n_in,
                              void* d_out, int out_size, void* d_ws, size_t ws_size,
                              hipStream_t stream) {
    const int* ei = (const int*)d_in[0];
    const float* xu = (const float*)d_in[1];
    const float* xi = (const float*)d_in[2];
    const float* W1 = (const float*)d_in[3];
    const float* attS1 = (const float*)d_in[4];
    const float* attD1 = (const float*)d_in[5];
    const float* b1 = (const float*)d_in[6];
    const float* W2 = (const float*)d_in[7];
    const float* attS2 = (const float*)d_in[8];
    const float* attD2 = (const float*)d_in[9];
    const float* b2 = (const float*)d_in[10];
    float* out = (float*)d_out;

    const int E = in_sizes[0] / 2;
    const int NU = in_sizes[1] / 64;
    const int NI = in_sizes[2] / 64;
    const int N = NU + NI;
    const int ET = E + N;

    char* p = (char*)d_ws;
    auto carve = [&](size_t bytes) {
        void* r = (void*)p;
        p += (bytes + 255) & ~(size_t)255;
        return r;
    };
    unsigned short* xb = (unsigned short*)carve((size_t)N * 64 * 2);   // 14 MB
    unsigned short* yb = (unsigned short*)carve((size_t)N * 256 * 2);  // 56 MB
    unsigned short* x2 = (unsigned short*)carve((size_t)N * 256 * 2);  // 56 MB
    float* as1 = (float*)carve((size_t)N * 4 * 4);
    float* ad1 = (float*)carve((size_t)N * 4 * 4);
    float* as2 = (float*)carve((size_t)N * 4);
    float* ad2 = (float*)carve((size_t)N * 4);
    float* attv1s = (float*)carve(256 * 4);
    float* attv1d = (float*)carve(256 * 4);
    float* attv2s = (float*)carve(256 * 4);
    float* attv2d = (float*)carve(256 * 4);
    int* offs = (int*)carve((size_t)(N + 1) * 4);
    int* cursor = (int*)carve((size_t)N * 4);
    int* csr = (int*)carve((size_t)ET * 4);
    int* bsums = (int*)carve(64 * 4);
    unsigned short* h2 = yb;  // yb dead after gemm_mid

    // --- small precomputes ---
    prep_attv_kernel<<<1, 256, 0, stream>>>(W1, attS1, attD1, W2, attS2, attD2,
                                            attv1s, attv1d, attv2s, attv2d);
    cast_att_kernel<<<(N + 3) / 4, 256, 0, stream>>>(xu, xi, NU, N, attv1s, attv1d,
                                                     xb, as1, ad1);

    // --- build CSR (grouped by dst) ---
    hipMemsetAsync(cursor, 0, (size_t)N * 4, stream);
    {
        int grid = (ET + 255) / 256;
        hist_kernel<<<grid, 256, 0, stream>>>(ei, E, ET, cursor);
    }
    {
        int nsb = (N + 4095) / 4096;
        scan_blocks_kernel<<<nsb, 256, 0, stream>>>(cursor, offs, bsums, N);
        scan_small_kernel<<<1, 64, 0, stream>>>(bsums, nsb);
        int grid = (N + 255) / 256;
        scan_add_kernel<<<grid, 256, 0, stream>>>(offs, bsums, N, ET);
    }
    hipMemcpyAsync(cursor, offs, (size_t)N * 4, hipMemcpyDeviceToDevice, stream);
    {
        int grid = (ET + 255) / 256;
        scatter_kernel<<<grid, 256, 0, stream>>>(ei, E, ET, cursor, csr);
    }

    // --- layer 1: aggregate x, then GEMM+ELU ---
    agg1_kernel<<<(N + 3) / 4, 256, 0, stream>>>(xb, as1, ad1, offs, csr, yb, N);
    gemm_mid_mfma<<<512, 256, 0, stream>>>(yb, N, W1, b1, attv2s, attv2d, x2, as2, ad2);

    // --- layer 2: GEMM, then aggregate h2 ---
    gemm2_mfma<<<512, 256, 0, stream>>>(x2, N, W2, h2);
    agg2_kernel<<<(N + 3) / 4, 256, 0, stream>>>(h2, as2, ad2, offs, csr, b2, out, N);
}